// Round 1
// baseline (11496.768 us; speedup 1.0000x reference)
//
#include <hip/hip_runtime.h>

#define B_ 64
#define T_ 512
#define D_ 1024
#define U_ 1024

typedef __attribute__((ext_vector_type(4))) float f32x4;
typedef __attribute__((ext_vector_type(8))) short bf16x8;
typedef __attribute__((ext_vector_type(4))) short s16x4;

__device__ __forceinline__ short f2bf(float f) {
  union { float f; unsigned u; } v; v.f = f;
  unsigned r = v.u + 0x7FFFu + ((v.u >> 16) & 1u);   // RNE
  return (short)(r >> 16);
}
__device__ __forceinline__ float bf2f(short s) {
  union { unsigned u; float f; } v; v.u = ((unsigned)(unsigned short)s) << 16;
  return v.f;
}

// Phase 1: XS[b*T+t][u] = sum_d X[b*T+t][d] * W[d][u]
// bf16 MFMA (16x16x32), fp32 accum, bf16 output into workspace.
// M=32768, N=1024, K=1024. BM=BN=128, BK=32. 256 threads = 4 waves (2x2),
// each wave owns a 64x64 sub-tile = 4x4 fragments of 16x16.
__global__ __launch_bounds__(256) void gemm_xw(
    const float* __restrict__ X, const float* __restrict__ W,
    short* __restrict__ XS) {
  // LDS layout [k-group][row][8 contiguous k] so each lane's frag is one ds_read_b128
  __shared__ __align__(16) short Asl[4][128][8];
  __shared__ __align__(16) short Bsl[4][128][8];
  const int tid = threadIdx.x;
  const int row0 = blockIdx.x * 128;
  const int col0 = blockIdx.y * 128;
  const int wave = tid >> 6, lane = tid & 63;
  const int wm = wave >> 1, wn = wave & 1;
  const int kg = lane >> 4, l16 = lane & 15;

  f32x4 acc[4][4] = {};

  for (int kt = 0; kt < 32; ++kt) {
    // ---- stage A (128x32 fp32 -> bf16) ----
    #pragma unroll
    for (int i = 0; i < 4; ++i) {
      int e = tid * 4 + i * 1024;
      int r = e >> 5, c = e & 31;
      const f32x4 v = *(const f32x4*)(X + (size_t)(row0 + r) * D_ + kt * 32 + c);
      s16x4 sv;
      sv.x = f2bf(v.x); sv.y = f2bf(v.y); sv.z = f2bf(v.z); sv.w = f2bf(v.w);
      *(s16x4*)&Asl[c >> 3][r][c & 7] = sv;
    }
    // ---- stage B (32x128 fp32 -> bf16), scatter into [kgroup][col][k] ----
    #pragma unroll
    for (int i = 0; i < 4; ++i) {
      int e = tid * 4 + i * 1024;
      int kr = e >> 7, c = e & 127;
      const f32x4 v = *(const f32x4*)(W + (size_t)(kt * 32 + kr) * U_ + col0 + c);
      Bsl[kr >> 3][c + 0][kr & 7] = f2bf(v.x);
      Bsl[kr >> 3][c + 1][kr & 7] = f2bf(v.y);
      Bsl[kr >> 3][c + 2][kr & 7] = f2bf(v.z);
      Bsl[kr >> 3][c + 3][kr & 7] = f2bf(v.w);
    }
    __syncthreads();
    bf16x8 af[4], bfv[4];
    #pragma unroll
    for (int m = 0; m < 4; ++m)
      af[m] = *(const bf16x8*)&Asl[kg][wm * 64 + m * 16 + l16][0];
    #pragma unroll
    for (int n = 0; n < 4; ++n)
      bfv[n] = *(const bf16x8*)&Bsl[kg][wn * 64 + n * 16 + l16][0];
    #pragma unroll
    for (int m = 0; m < 4; ++m) {
      #pragma unroll
      for (int n = 0; n < 4; ++n)
        acc[m][n] = __builtin_amdgcn_mfma_f32_16x16x32_bf16(af[m], bfv[n], acc[m][n], 0, 0, 0);
    }
    __syncthreads();
  }
  // epilogue: C/D layout col=lane&15, row=(lane>>4)*4+reg  [HW-verified]
  #pragma unroll
  for (int m = 0; m < 4; ++m) {
    #pragma unroll
    for (int n = 0; n < 4; ++n) {
      const int grow0 = row0 + wm * 64 + m * 16 + (lane >> 4) * 4;
      const int gcol  = col0 + wn * 64 + n * 16 + l16;
      #pragma unroll
      for (int r = 0; r < 4; ++r)
        XS[(size_t)(grow0 + r) * U_ + gcol] = f2bf(acc[m][n][r]);
    }
  }
}

// Phase 2 (one timestep): hout[b][u] = bf2f(XS[b*T+t][u]) + sum_k hprev[b][k]*Umat[k][u]
// fp32 vector ALU. Grid (8,16)=128 blocks; block tile = 8 rows x 64 cols;
// 256 threads = 4 waves, wave w owns rows {2w, 2w+1}, lane = col.
__global__ __launch_bounds__(256) void scan_step(
    const float* __restrict__ hprev, const float* __restrict__ Umat,
    const short* __restrict__ XS, const int t, float* __restrict__ hout) {
  __shared__ float h_s[8][1024];
  const int tid = threadIdx.x;
  const int rb = blockIdx.x;   // row group: rows rb*8 .. rb*8+7
  const int cb = blockIdx.y;   // col group: cols cb*64 ..
  #pragma unroll
  for (int i = 0; i < 8; ++i)
    *(f32x4*)&h_s[i][tid * 4] =
        *(const f32x4*)(hprev + (size_t)(rb * 8 + i) * U_ + tid * 4);
  __syncthreads();

  const int wave = tid >> 6, lane = tid & 63;
  const int col = cb * 64 + lane;
  const int r0 = wave * 2, r1 = r0 + 1;
  const float* uc = Umat + col;
  float acc0 = 0.f, acc1 = 0.f;
  #pragma unroll 4
  for (int k = 0; k < 1024; k += 4) {
    f32x4 a = *(const f32x4*)&h_s[r0][k];
    f32x4 b = *(const f32x4*)&h_s[r1][k];
    float u0 = uc[(size_t)(k + 0) << 10];
    float u1 = uc[(size_t)(k + 1) << 10];
    float u2 = uc[(size_t)(k + 2) << 10];
    float u3 = uc[(size_t)(k + 3) << 10];
    acc0 = fmaf(a.x, u0, acc0); acc0 = fmaf(a.y, u1, acc0);
    acc0 = fmaf(a.z, u2, acc0); acc0 = fmaf(a.w, u3, acc0);
    acc1 = fmaf(b.x, u0, acc1); acc1 = fmaf(b.y, u1, acc1);
    acc1 = fmaf(b.z, u2, acc1); acc1 = fmaf(b.w, u3, acc1);
  }
  const int grow0 = rb * 8 + r0, grow1 = rb * 8 + r1;
  hout[(size_t)grow0 * U_ + col] =
      acc0 + bf2f(XS[((size_t)grow0 * T_ + t) * U_ + col]);
  hout[(size_t)grow1 * U_ + col] =
      acc1 + bf2f(XS[((size_t)grow1 * T_ + t) * U_ + col]);
}

extern "C" void kernel_launch(void* const* d_in, const int* in_sizes, int n_in,
                              void* d_out, int out_size, void* d_ws, size_t ws_size,
                              hipStream_t stream) {
  const float* X    = (const float*)d_in[0];  // [B,T,D]
  const float* W    = (const float*)d_in[1];  // [D,U]
  const float* Umat = (const float*)d_in[2];  // [U,U]
  float* out = (float*)d_out;                 // [B,U]

  char* ws = (char*)d_ws;
  short* XS = (short*)ws;                                  // bf16 [B*T, U] = 64 MiB
  float* h0 = (float*)(ws + (size_t)B_ * T_ * U_ * 2);     // fp32 [B,U]
  float* h1 = h0 + B_ * U_;

  // Phase 1: xs = x @ W
  gemm_xw<<<dim3(256, 8), 256, 0, stream>>>(X, W, XS);

  // h_0 = 0
  hipMemsetAsync(h0, 0, (size_t)B_ * U_ * sizeof(float), stream);

  // Phase 2: sequential scan, double-buffered h; last step writes d_out
  for (int t = 0; t < T_; ++t) {
    const float* hin = (t & 1) ? h1 : h0;
    float* ho = (t == T_ - 1) ? out : ((t & 1) ? h0 : h1);
    scan_step<<<dim3(8, 16), 256, 0, stream>>>(hin, Umat, XS, t, ho);
  }
}

// Round 2
// 1453.247 us; speedup vs baseline: 7.9111x; 7.9111x over previous
//
#include <hip/hip_runtime.h>

#define B_ 64
#define T_ 512
#define D_ 1024
#define U_ 1024

typedef __attribute__((ext_vector_type(4))) float f32x4;
typedef __attribute__((ext_vector_type(8))) short bf16x8;
typedef __attribute__((ext_vector_type(4))) short s16x4;

__device__ __forceinline__ short f2bf(float f) {
  union { float f; unsigned u; } v; v.f = f;
  unsigned r = v.u + 0x7FFFu + ((v.u >> 16) & 1u);   // RNE
  return (short)(r >> 16);
}
__device__ __forceinline__ float bf2f(short s) {
  union { unsigned u; float f; } v; v.u = ((unsigned)(unsigned short)s) << 16;
  return v.f;
}

// ---------------- Phase 1: XS[b*T+t][u] = sum_d X[.][d] * W[d][u]  (verified) ----
__global__ __launch_bounds__(256) void gemm_xw(
    const float* __restrict__ X, const float* __restrict__ W,
    short* __restrict__ XS) {
  __shared__ __align__(16) short Asl[4][128][8];
  __shared__ __align__(16) short Bsl[4][128][8];
  const int tid = threadIdx.x;
  const int row0 = blockIdx.x * 128;
  const int col0 = blockIdx.y * 128;
  const int wave = tid >> 6, lane = tid & 63;
  const int wm = wave >> 1, wn = wave & 1;
  const int kg = lane >> 4, l16 = lane & 15;

  f32x4 acc[4][4] = {};

  for (int kt = 0; kt < 32; ++kt) {
    #pragma unroll
    for (int i = 0; i < 4; ++i) {
      int e = tid * 4 + i * 1024;
      int r = e >> 5, c = e & 31;
      const f32x4 v = *(const f32x4*)(X + (size_t)(row0 + r) * D_ + kt * 32 + c);
      s16x4 sv;
      sv.x = f2bf(v.x); sv.y = f2bf(v.y); sv.z = f2bf(v.z); sv.w = f2bf(v.w);
      *(s16x4*)&Asl[c >> 3][r][c & 7] = sv;
    }
    #pragma unroll
    for (int i = 0; i < 4; ++i) {
      int e = tid * 4 + i * 1024;
      int kr = e >> 7, c = e & 127;
      const f32x4 v = *(const f32x4*)(W + (size_t)(kt * 32 + kr) * U_ + col0 + c);
      Bsl[kr >> 3][c + 0][kr & 7] = f2bf(v.x);
      Bsl[kr >> 3][c + 1][kr & 7] = f2bf(v.y);
      Bsl[kr >> 3][c + 2][kr & 7] = f2bf(v.z);
      Bsl[kr >> 3][c + 3][kr & 7] = f2bf(v.w);
    }
    __syncthreads();
    bf16x8 af[4], bfv[4];
    #pragma unroll
    for (int m = 0; m < 4; ++m)
      af[m] = *(const bf16x8*)&Asl[kg][wm * 64 + m * 16 + l16][0];
    #pragma unroll
    for (int n = 0; n < 4; ++n)
      bfv[n] = *(const bf16x8*)&Bsl[kg][wn * 64 + n * 16 + l16][0];
    #pragma unroll
    for (int m = 0; m < 4; ++m) {
      #pragma unroll
      for (int n = 0; n < 4; ++n)
        acc[m][n] = __builtin_amdgcn_mfma_f32_16x16x32_bf16(af[m], bfv[n], acc[m][n], 0, 0, 0);
    }
    __syncthreads();
  }
  #pragma unroll
  for (int m = 0; m < 4; ++m) {
    #pragma unroll
    for (int n = 0; n < 4; ++n) {
      const int grow0 = row0 + wm * 64 + m * 16 + (lane >> 4) * 4;
      const int gcol  = col0 + wn * 64 + n * 16 + l16;
      #pragma unroll
      for (int r = 0; r < 4; ++r)
        XS[(size_t)(grow0 + r) * U_ + gcol] = f2bf(acc[m][n][r]);
    }
  }
}

// ---------------- cast U (fp32) -> P0 (bf16) ----------------
__global__ __launch_bounds__(256) void castU(const float* __restrict__ Um,
                                             short* __restrict__ P) {
  const int base = (blockIdx.x * 256 + threadIdx.x) * 8;
  f32x4 a = *(const f32x4*)(Um + base);
  f32x4 b = *(const f32x4*)(Um + base + 4);
  bf16x8 o;
  o[0] = f2bf(a.x); o[1] = f2bf(a.y); o[2] = f2bf(a.z); o[3] = f2bf(a.w);
  o[4] = f2bf(b.x); o[5] = f2bf(b.y); o[6] = f2bf(b.z); o[7] = f2bf(b.w);
  *(bf16x8*)(P + base) = o;
}

// ---------------- power squaring: C = A * B (all bf16 [1024][1024]) ----------
__global__ __launch_bounds__(256) void gemm_pp(
    const short* __restrict__ A, const short* __restrict__ Bm,
    short* __restrict__ C) {
  __shared__ __align__(16) short Asl[4][128][8];
  __shared__ __align__(16) short Bsl[4][128][8];
  const int tid = threadIdx.x;
  const int row0 = blockIdx.x * 128;
  const int col0 = blockIdx.y * 128;
  const int wave = tid >> 6, lane = tid & 63;
  const int wm = wave >> 1, wn = wave & 1;
  const int kg = lane >> 4, l16 = lane & 15;

  f32x4 acc[4][4] = {};

  for (int kt = 0; kt < 32; ++kt) {
    #pragma unroll
    for (int j = 0; j < 2; ++j) {
      int g = tid + j * 256;           // 512 granules of 8 bf16
      int r = g >> 2, kc = (g & 3) * 8;
      *(bf16x8*)&Asl[g & 3][r][0] =
          *(const bf16x8*)(A + (size_t)(row0 + r) * U_ + kt * 32 + kc);
    }
    #pragma unroll
    for (int j = 0; j < 2; ++j) {
      int g = tid + j * 256;
      int kr = g >> 4, c = (g & 15) * 8;
      bf16x8 v = *(const bf16x8*)(Bm + (size_t)(kt * 32 + kr) * U_ + col0 + c);
      #pragma unroll
      for (int i = 0; i < 8; ++i) Bsl[kr >> 3][c + i][kr & 7] = v[i];
    }
    __syncthreads();
    bf16x8 af[4], bfv[4];
    #pragma unroll
    for (int m = 0; m < 4; ++m)
      af[m] = *(const bf16x8*)&Asl[kg][wm * 64 + m * 16 + l16][0];
    #pragma unroll
    for (int n = 0; n < 4; ++n)
      bfv[n] = *(const bf16x8*)&Bsl[kg][wn * 64 + n * 16 + l16][0];
    #pragma unroll
    for (int m = 0; m < 4; ++m)
      #pragma unroll
      for (int n = 0; n < 4; ++n)
        acc[m][n] = __builtin_amdgcn_mfma_f32_16x16x32_bf16(af[m], bfv[n], acc[m][n], 0, 0, 0);
    __syncthreads();
  }
  #pragma unroll
  for (int m = 0; m < 4; ++m) {
    #pragma unroll
    for (int n = 0; n < 4; ++n) {
      const int grow0 = row0 + wm * 64 + m * 16 + (lane >> 4) * 4;
      const int gcol  = col0 + wn * 64 + n * 16 + l16;
      #pragma unroll
      for (int r = 0; r < 4; ++r)
        C[(size_t)(grow0 + r) * U_ + gcol] = f2bf(acc[m][n][r]);
    }
  }
}

// ---------------- combine level: Fout[R] = Fin[mul(R)] * P + Fin[add(R)] ------
// L0: Fin = XS (bf16), seg len 1 in (b,t) layout: mul = (b<<9)|(2s), add = mul+1
// else: Fin = F (fp32), seg-major:              mul = (s<<7)|b,     add = mul+64
template<bool L0>
__global__ __launch_bounds__(256) void combine(
    const void* __restrict__ Fin_, const short* __restrict__ P,
    float* __restrict__ Fout, float* __restrict__ hout) {
  __shared__ __align__(16) short Asl[4][128][8];
  __shared__ __align__(16) short Bsl[4][128][8];
  const short* FinB = (const short*)Fin_;
  const float* FinF = (const float*)Fin_;
  const int tid = threadIdx.x;
  const int row0 = blockIdx.x * 128;
  const int col0 = blockIdx.y * 128;
  const int wave = tid >> 6, lane = tid & 63;
  const int wm = wave >> 1, wn = wave & 1;
  const int kg = lane >> 4, l16 = lane & 15;

  f32x4 acc[4][4] = {};

  for (int kt = 0; kt < 32; ++kt) {
    if (L0) {
      #pragma unroll
      for (int j = 0; j < 2; ++j) {
        int g = tid + j * 256;
        int r = g >> 2, kc = (g & 3) * 8;
        int R = row0 + r;
        int mr = ((R & 63) << 9) | ((R >> 6) << 1);
        *(bf16x8*)&Asl[g & 3][r][0] =
            *(const bf16x8*)(FinB + (size_t)mr * U_ + kt * 32 + kc);
      }
    } else {
      #pragma unroll
      for (int j = 0; j < 4; ++j) {
        int g = tid + j * 256;           // 1024 granules of 4 fp32
        int r = g >> 3, kc = (g & 7) * 4;
        int R = row0 + r;
        int mr = ((R >> 6) << 7) | (R & 63);
        f32x4 v = *(const f32x4*)(FinF + (size_t)mr * U_ + kt * 32 + kc);
        s16x4 sv;
        sv.x = f2bf(v.x); sv.y = f2bf(v.y); sv.z = f2bf(v.z); sv.w = f2bf(v.w);
        *(s16x4*)&Asl[kc >> 3][r][kc & 7] = sv;
      }
    }
    #pragma unroll
    for (int j = 0; j < 2; ++j) {
      int g = tid + j * 256;
      int kr = g >> 4, c = (g & 15) * 8;
      bf16x8 v = *(const bf16x8*)(P + (size_t)(kt * 32 + kr) * U_ + col0 + c);
      #pragma unroll
      for (int i = 0; i < 8; ++i) Bsl[kr >> 3][c + i][kr & 7] = v[i];
    }
    __syncthreads();
    bf16x8 af[4], bfv[4];
    #pragma unroll
    for (int m = 0; m < 4; ++m)
      af[m] = *(const bf16x8*)&Asl[kg][wm * 64 + m * 16 + l16][0];
    #pragma unroll
    for (int n = 0; n < 4; ++n)
      bfv[n] = *(const bf16x8*)&Bsl[kg][wn * 64 + n * 16 + l16][0];
    #pragma unroll
    for (int m = 0; m < 4; ++m)
      #pragma unroll
      for (int n = 0; n < 4; ++n)
        acc[m][n] = __builtin_amdgcn_mfma_f32_16x16x32_bf16(af[m], bfv[n], acc[m][n], 0, 0, 0);
    __syncthreads();
  }
  #pragma unroll
  for (int m = 0; m < 4; ++m) {
    #pragma unroll
    for (int n = 0; n < 4; ++n) {
      const int grow0 = row0 + wm * 64 + m * 16 + (lane >> 4) * 4;
      const int gcol  = col0 + wn * 64 + n * 16 + l16;
      #pragma unroll
      for (int r = 0; r < 4; ++r) {
        const int R = grow0 + r;
        int ar;
        float add;
        if (L0) {
          ar = (((R & 63) << 9) | ((R >> 6) << 1)) + 1;
          add = bf2f(FinB[(size_t)ar * U_ + gcol]);
        } else {
          ar = (((R >> 6) << 7) | (R & 63)) + 64;
          add = FinF[(size_t)ar * U_ + gcol];
        }
        const float val = acc[m][n][r] + add;
        Fout[(size_t)R * U_ + gcol] = val;
        if (hout != nullptr && R < B_) hout[(size_t)R * U_ + gcol] = val;
      }
    }
  }
}

extern "C" void kernel_launch(void* const* d_in, const int* in_sizes, int n_in,
                              void* d_out, int out_size, void* d_ws, size_t ws_size,
                              hipStream_t stream) {
  const float* X    = (const float*)d_in[0];  // [B,T,D]
  const float* W    = (const float*)d_in[1];  // [D,U]
  const float* Umat = (const float*)d_in[2];  // [U,U]
  float* out = (float*)d_out;                 // [B,U]

  char* ws = (char*)d_ws;
  short* XS   = (short*)ws;                        // bf16 [32768,1024] = 64 MB (regB)
  float* regB = (float*)ws;                        // fp32 F buffers alias dead XS
  float* regA = (float*)(ws + ((size_t)64 << 20)); // fp32 up to [16384,1024] = 64 MB
  short* P0   = (short*)(ws + ((size_t)128 << 20));// bf16 [1024,1024] = 2 MB
  short* P1   = (short*)(ws + ((size_t)130 << 20));// bf16 [1024,1024] = 2 MB

  // Phase 1: xs = x @ W  (bf16 out)
  gemm_xw<<<dim3(256, 8), 256, 0, stream>>>(X, W, XS);
  castU<<<512, 256, 0, stream>>>(Umat, P0);

  short* Pcur = P0;
  short* Pnxt = P1;

  // Level 0: F1 = XS[even]*U + XS[odd]   (M = 16384)
  combine<true><<<dim3(128, 8), 256, 0, stream>>>(XS, Pcur, regA, nullptr);
  gemm_pp<<<dim3(8, 8), 256, 0, stream>>>(Pcur, Pcur, Pnxt);
  { short* t = Pcur; Pcur = Pnxt; Pnxt = t; }

  float* fin  = regA;
  float* fout = regB;
  for (int k = 1; k <= 8; ++k) {
    const int Mout  = 16384 >> k;                   // 8192 ... 64
    const int gridx = (Mout >= 128) ? (Mout / 128) : 1;
    float* hptr = (k == 8) ? out : nullptr;
    combine<false><<<dim3(gridx, 8), 256, 0, stream>>>(fin, Pcur, fout, hptr);
    if (k < 8) {
      gemm_pp<<<dim3(8, 8), 256, 0, stream>>>(Pcur, Pcur, Pnxt);
      { short* t = Pcur; Pcur = Pnxt; Pnxt = t; }
    }
    { float* t = fin; fin = fout; fout = t; }
  }
}

// Round 3
// 487.983 us; speedup vs baseline: 23.5598x; 2.9781x over previous
//
#include <hip/hip_runtime.h>
#include <hip/hip_bf16.h>

typedef __attribute__((ext_vector_type(4))) float f32x4;
typedef __attribute__((ext_vector_type(8))) short bf16x8;
typedef __attribute__((ext_vector_type(4))) short s16x4;

__device__ __forceinline__ short f2bfs(float f) {
  __hip_bfloat16 h = __float2bfloat16(f);          // RNE; compiler fuses pairs to v_cvt_pk_bf16_f32
  union { __hip_bfloat16 h; short s; } u; u.h = h;
  return u.s;
}
__device__ __forceinline__ float bf2fs(short s) {
  union { unsigned u; float f; } v; v.u = ((unsigned)(unsigned short)s) << 16;
  return v.f;
}

// async global->LDS, 16B per lane; LDS dest = wave-uniform base + lane*16 (linear)
__device__ __forceinline__ void gload16(void* l, const void* g) {
  __builtin_amdgcn_global_load_lds(
      (const __attribute__((address_space(1))) unsigned int*)g,
      (__attribute__((address_space(3))) unsigned int*)l, 16, 0, 0);
}

// ---------------------------------------------------------------------------
// Core K=1024 GEMM pass: C += A(row-major, via ROWMAP) * BT(row-major [n][k])^T
// 128x128 tile, 4 waves (2x2), 16x16x32 bf16 MFMA, BK=32, 2 barriers/K-step.
// Staging: global_load_lds with pre-swizzled SOURCE; ds_read with same XOR.
//   bf16 tile [128][32]: granule(16B)=8 bf16, 4/row, swz g^((r>>1)&3)
//   fp32 tile [128][32]: granule=4 f32, 8/row,     swz g^(r&7)
// ROWMAP: 0 identity; 1 radix-4 (XS row = (R&63)*512 + 4*(R>>6) + j4);
//         2 radix-2 (row = (R>>6)*128 + (R&63))
// ---------------------------------------------------------------------------
template<int ABF16, int ROWMAP>
__device__ __forceinline__ void gemm_pass(
    char* lds, f32x4 (&acc)[4][4],
    const void* __restrict__ Ap, const short* __restrict__ BTp,
    int row0, int col0, int j4, int tid, int wave, int lane) {
  char* ldsB = lds + (ABF16 ? 8192 : 16384);
  const int wm = wave >> 1, wn = wave & 1;
  const int l16 = lane & 15, kg = lane >> 4;

  for (int kt = 0; kt < 32; ++kt) {
    if (ABF16) {
      const short* A = (const short*)Ap;
      #pragma unroll
      for (int i = 0; i < 2; ++i) {
        int G = i * 256 + tid;
        int r = G >> 2, g = G & 3;
        int R = row0 + r;
        int mr = (ROWMAP == 0) ? R
               : (ROWMAP == 1) ? ((((R & 63) << 9) | ((R >> 6) << 2)) + j4)
                               : (((R >> 6) << 7) | (R & 63));
        int gs = g ^ ((r >> 1) & 3);
        gload16(lds + (size_t)G * 16, A + (size_t)mr * 1024 + kt * 32 + gs * 8);
      }
    } else {
      const float* A = (const float*)Ap;
      #pragma unroll
      for (int i = 0; i < 4; ++i) {
        int G = i * 256 + tid;
        int r = G >> 3, g = G & 7;
        int R = row0 + r;
        int mr = (ROWMAP == 0) ? R
               : (ROWMAP == 1) ? ((((R & 63) << 9) | ((R >> 6) << 2)) + j4)
                               : (((R >> 6) << 7) | (R & 63));
        int gs = g ^ (r & 7);
        gload16(lds + (size_t)G * 16, A + (size_t)mr * 1024 + kt * 32 + gs * 4);
      }
    }
    #pragma unroll
    for (int i = 0; i < 2; ++i) {
      int G = i * 256 + tid;
      int r = G >> 2, g = G & 3;
      int gs = g ^ ((r >> 1) & 3);
      gload16(ldsB + (size_t)G * 16, BTp + (size_t)(col0 + r) * 1024 + kt * 32 + gs * 8);
    }
    __syncthreads();   // drains vmcnt -> staging complete

    bf16x8 af[4], bfr[4];
    #pragma unroll
    for (int m = 0; m < 4; ++m) {
      int row = wm * 64 + m * 16 + l16;
      if (ABF16) {
        int g = kg ^ ((row >> 1) & 3);
        af[m] = *(const bf16x8*)(lds + (row * 4 + g) * 16);
      } else {
        int sw = row & 7;
        f32x4 lo = *(const f32x4*)(lds + (row * 8 + ((2 * kg) ^ sw)) * 16);
        f32x4 hi = *(const f32x4*)(lds + (row * 8 + ((2 * kg + 1) ^ sw)) * 16);
        bf16x8 t;
        t[0] = f2bfs(lo.x); t[1] = f2bfs(lo.y); t[2] = f2bfs(lo.z); t[3] = f2bfs(lo.w);
        t[4] = f2bfs(hi.x); t[5] = f2bfs(hi.y); t[6] = f2bfs(hi.z); t[7] = f2bfs(hi.w);
        af[m] = t;
      }
    }
    #pragma unroll
    for (int n = 0; n < 4; ++n) {
      int c = wn * 64 + n * 16 + l16;
      int g = kg ^ ((c >> 1) & 3);
      bfr[n] = *(const bf16x8*)(ldsB + (c * 4 + g) * 16);
    }
    #pragma unroll
    for (int m = 0; m < 4; ++m)
      #pragma unroll
      for (int n = 0; n < 4; ++n)
        acc[m][n] = __builtin_amdgcn_mfma_f32_16x16x32_bf16(af[m], bfr[n], acc[m][n], 0, 0, 0);
    __syncthreads();   // protect LDS before next-step staging
  }
}

// epilogue: C/D layout col=lane&15, row=(lane>>4)*4+reg  [HW-verified]
// ADDMODE: 0 none; 1 radix-4 add = XS row +3 (bf16); 2 radix-2 add row +64 (fp32)
template<int ADDMODE, int OUTBF, bool HOUT>
__device__ __forceinline__ void gemm_epi(
    f32x4 (&acc)[4][4], void* __restrict__ Cp, const void* __restrict__ AddP,
    float* __restrict__ hout, int row0, int col0, int wave, int lane) {
  const int wm = wave >> 1, wn = wave & 1;
  const int l16 = lane & 15;
  #pragma unroll
  for (int m = 0; m < 4; ++m) {
    #pragma unroll
    for (int n = 0; n < 4; ++n) {
      const int grow0 = row0 + wm * 64 + m * 16 + ((lane >> 4) << 2);
      const int gcol  = col0 + wn * 64 + n * 16 + l16;
      #pragma unroll
      for (int r = 0; r < 4; ++r) {
        const int R = grow0 + r;
        float val = acc[m][n][r];
        if (ADDMODE == 1) {
          int ar = (((R & 63) << 9) | ((R >> 6) << 2)) + 3;
          val += bf2fs(((const short*)AddP)[(size_t)ar * 1024 + gcol]);
        } else if (ADDMODE == 2) {
          int ar = (((R >> 6) << 7) | (R & 63)) + 64;
          val += ((const float*)AddP)[(size_t)ar * 1024 + gcol];
        }
        if (OUTBF) ((short*)Cp)[(size_t)R * 1024 + gcol] = f2bfs(val);
        else       ((float*)Cp)[(size_t)R * 1024 + gcol] = val;
        if (HOUT) { if (R < 64) hout[(size_t)R * 1024 + gcol] = val; }
      }
    }
  }
}

// ---------------- prep: WT = W^T (bf16), PT0 = U^T (bf16), P0 = U (bf16) ----
__global__ __launch_bounds__(256) void k_prep(
    const float* __restrict__ W, const float* __restrict__ U,
    short* __restrict__ WT, short* __restrict__ PT0, short* __restrict__ P0) {
  __shared__ float tf[32][36];
  int b = blockIdx.x, t = threadIdx.x;
  if (b < 2048) {
    const float* src = (b < 1024) ? W : U;
    short* dst = (b < 1024) ? WT : PT0;
    int bb = b & 1023;
    int i0 = (bb >> 5) * 32, j0 = (bb & 31) * 32;
    int r = t >> 3, c = (t & 7) * 4;
    *(f32x4*)&tf[r][c] = *(const f32x4*)(src + (size_t)(i0 + r) * 1024 + j0 + c);
    __syncthreads();
    s16x4 o;
    o.x = f2bfs(tf[c + 0][r]); o.y = f2bfs(tf[c + 1][r]);
    o.z = f2bfs(tf[c + 2][r]); o.w = f2bfs(tf[c + 3][r]);
    *(s16x4*)(dst + (size_t)(j0 + r) * 1024 + i0 + c) = o;
  } else {
    int q = b - 2048;
    size_t base = (size_t)q * 2048 + (size_t)t * 8;
    f32x4 a = *(const f32x4*)(U + base);
    f32x4 c2 = *(const f32x4*)(U + base + 4);
    bf16x8 o;
    o[0] = f2bfs(a.x);  o[1] = f2bfs(a.y);  o[2] = f2bfs(a.z);  o[3] = f2bfs(a.w);
    o[4] = f2bfs(c2.x); o[5] = f2bfs(c2.y); o[6] = f2bfs(c2.z); o[7] = f2bfs(c2.w);
    *(bf16x8*)(P0 + base) = o;
  }
}

// ---------------- Phase 1: XS = X * WT^T  (fp32 A, bf16 out) ----------------
__global__ __launch_bounds__(256) void k_xw(
    const float* __restrict__ X, const short* __restrict__ WT,
    short* __restrict__ XS) {
  __shared__ __align__(16) char lds[24576];
  f32x4 acc[4][4] = {};
  int tid = threadIdx.x, wave = tid >> 6, lane = tid & 63;
  gemm_pass<0, 0>(lds, acc, X, WT, blockIdx.x * 128, blockIdx.y * 128, 0, tid, wave, lane);
  gemm_epi<0, 1, false>(acc, XS, nullptr, nullptr, blockIdx.x * 128, blockIdx.y * 128, wave, lane);
}

// ---------------- standalone square / power (grid 128 => both P,PT; 64 => one)
__global__ __launch_bounds__(256) void k_sq(
    const short* __restrict__ P, const short* __restrict__ PT,
    short* __restrict__ Pn, short* __restrict__ PTn) {
  __shared__ __align__(16) char lds[16384];
  int b = blockIdx.x; int z = b >> 6; int q = b & 63;
  int row0 = (q >> 3) * 128, col0 = (q & 7) * 128;
  f32x4 acc[4][4] = {};
  int tid = threadIdx.x, wave = tid >> 6, lane = tid & 63;
  if (z == 0) {
    gemm_pass<1, 0>(lds, acc, P, PT, row0, col0, 0, tid, wave, lane);
    gemm_epi<0, 1, false>(acc, Pn, nullptr, nullptr, row0, col0, wave, lane);
  } else {
    gemm_pass<1, 0>(lds, acc, PT, P, row0, col0, 0, tid, wave, lane);
    gemm_epi<0, 1, false>(acc, PTn, nullptr, nullptr, row0, col0, wave, lane);
  }
}

// ---------------- Level 0 (radix-4) + fused square of U^2 -> U^4 ------------
// combine blocks (512): F1[s*64+b] = XS[4s]*U^3 + XS[4s+1]*U^2 + XS[4s+2]*U + XS[4s+3]
__global__ __launch_bounds__(256) void k_l0(
    const short* __restrict__ XS,
    const short* __restrict__ PT0, const short* __restrict__ PT1,
    const short* __restrict__ PT3, float* __restrict__ F1,
    const short* __restrict__ Psq, const short* __restrict__ PTsq,
    short* __restrict__ Pn, short* __restrict__ PTn) {
  __shared__ __align__(16) char lds[16384];
  f32x4 acc[4][4] = {};
  int tid = threadIdx.x, wave = tid >> 6, lane = tid & 63;
  int b = blockIdx.x;
  if (b < 512) {
    int row0 = (b >> 3) * 128, col0 = (b & 7) * 128;
    gemm_pass<1, 1>(lds, acc, XS, PT3, row0, col0, 0, tid, wave, lane);
    gemm_pass<1, 1>(lds, acc, XS, PT1, row0, col0, 1, tid, wave, lane);
    gemm_pass<1, 1>(lds, acc, XS, PT0, row0, col0, 2, tid, wave, lane);
    gemm_epi<1, 0, false>(acc, F1, XS, nullptr, row0, col0, wave, lane);
  } else {
    int q = b - 512; int z = q >> 6; q &= 63;
    int row0 = (q >> 3) * 128, col0 = (q & 7) * 128;
    if (z == 0) {
      gemm_pass<1, 0>(lds, acc, Psq, PTsq, row0, col0, 0, tid, wave, lane);
      gemm_epi<0, 1, false>(acc, Pn, nullptr, nullptr, row0, col0, wave, lane);
    } else {
      gemm_pass<1, 0>(lds, acc, PTsq, Psq, row0, col0, 0, tid, wave, lane);
      gemm_epi<0, 1, false>(acc, PTn, nullptr, nullptr, row0, col0, wave, lane);
    }
  }
}

// ---------------- radix-2 level + fused square (except LAST) ----------------
template<bool LAST>
__global__ __launch_bounds__(256) void k_lvl(
    const float* __restrict__ Fin, const short* __restrict__ PTu,
    float* __restrict__ Fout, float* __restrict__ hout,
    const short* __restrict__ Psq, const short* __restrict__ PTsq,
    short* __restrict__ Pn, short* __restrict__ PTn, int nComb) {
  __shared__ __align__(16) char lds[24576];
  f32x4 acc[4][4] = {};
  int tid = threadIdx.x, wave = tid >> 6, lane = tid & 63;
  int b = blockIdx.x;
  if (b < nComb) {
    int row0 = (b >> 3) * 128, col0 = (b & 7) * 128;
    gemm_pass<0, 2>(lds, acc, Fin, PTu, row0, col0, 0, tid, wave, lane);
    gemm_epi<2, 0, LAST>(acc, Fout, Fin, hout, row0, col0, wave, lane);
  } else {
    int q = b - nComb; int z = q >> 6; q &= 63;
    int row0 = (q >> 3) * 128, col0 = (q & 7) * 128;
    if (z == 0) {
      gemm_pass<1, 0>(lds, acc, Psq, PTsq, row0, col0, 0, tid, wave, lane);
      gemm_epi<0, 1, false>(acc, Pn, nullptr, nullptr, row0, col0, wave, lane);
    } else {
      gemm_pass<1, 0>(lds, acc, PTsq, Psq, row0, col0, 0, tid, wave, lane);
      gemm_epi<0, 1, false>(acc, PTn, nullptr, nullptr, row0, col0, wave, lane);
    }
  }
}

extern "C" void kernel_launch(void* const* d_in, const int* in_sizes, int n_in,
                              void* d_out, int out_size, void* d_ws, size_t ws_size,
                              hipStream_t stream) {
  const float* X = (const float*)d_in[0];   // [64,512,1024]
  const float* W = (const float*)d_in[1];   // [1024,1024]
  const float* U = (const float*)d_in[2];   // [1024,1024]
  float* out = (float*)d_out;               // [64,1024]

  char* ws = (char*)d_ws;
  short* XS = (short*)ws;                                  // bf16 [32768,1024]  [0,64MB)
  float* S0 = (float*)(ws + ((size_t)64 << 20));           // fp32, up to 32MB   [64,96)
  float* S1 = (float*)(ws + ((size_t)96 << 20));           // fp32, up to 16MB   [96,112)
  char* pb = ws + ((size_t)112 << 20);                     // power slots, 2MB each
  const size_t SL = (size_t)2 << 20;
  short* Pa  = (short*)(pb + 0 * SL);
  short* Pb  = (short*)(pb + 1 * SL);
  short* PT0 = (short*)(pb + 2 * SL);
  short* PT1 = (short*)(pb + 3 * SL);
  short* PT3 = (short*)(pb + 4 * SL);
  short* PTa = (short*)(pb + 5 * SL);
  short* PTb = (short*)(pb + 6 * SL);
  short* WT  = PTa;   // WT dead before PTa is first written (at k_l0)

  k_prep<<<2560, 256, 0, stream>>>(W, U, WT, PT0, Pa);           // WT, U^T, U
  k_xw<<<dim3(256, 8), 256, 0, stream>>>(X, WT, XS);             // XS = X W
  k_sq<<<128, 256, 0, stream>>>(Pa, PT0, Pb, PT1);               // U^2, U^2T
  k_sq<<<64, 256, 0, stream>>>(PT1, Pa, PT3, nullptr);           // PT3 = U^3T
  // L0 radix-4 (F1: M=8192) + square U^2 -> U^4 (Pa, PTa)
  k_l0<<<640, 256, 0, stream>>>(XS, PT0, PT1, PT3, S0, Pb, PT1, Pa, PTa);

  float* fin = S0; float* fout = S1;
  short* Pc = Pa;  short* PTc = PTa;    // current power = U^4
  short* Pn = Pb;  short* PTn = PTb;
  int Mout = 4096;
  for (int k = 1; k <= 7; ++k) {
    int nCx = (Mout >= 128) ? (Mout / 128) : 1;
    int nComb = nCx * 8;
    if (k < 7) {
      k_lvl<false><<<nComb + 128, 256, 0, stream>>>(fin, PTc, fout, nullptr,
                                                    Pc, PTc, Pn, PTn, nComb);
      short* tp = Pc; Pc = Pn; Pn = tp;
      short* tt = PTc; PTc = PTn; PTn = tt;
    } else {
      k_lvl<true><<<nComb, 256, 0, stream>>>(fin, PTc, fout, out,
                                             nullptr, nullptr, nullptr, nullptr, nComb);
    }
    float* tf = fin; fin = fout; fout = tf;
    Mout >>= 1;
  }
}

// Round 4
// 405.824 us; speedup vs baseline: 28.3294x; 1.2024x over previous
//
#include <hip/hip_runtime.h>
#include <hip/hip_bf16.h>

typedef __attribute__((ext_vector_type(4))) float f32x4;
typedef __attribute__((ext_vector_type(8))) short bf16x8;
typedef __attribute__((ext_vector_type(4))) short s16x4;

__device__ __forceinline__ short f2bfs(float f) {
  __hip_bfloat16 h = __float2bfloat16(f);   // RNE
  union { __hip_bfloat16 h; short s; } u; u.h = h;
  return u.s;
}
__device__ __forceinline__ float bf2fs(short s) {
  union { unsigned u; float f; } v; v.u = ((unsigned)(unsigned short)s) << 16;
  return v.f;
}

// async global->LDS, 16B/lane; LDS dest linear (wave base + lane*16)
__device__ __forceinline__ void gload16(void* l, const void* g) {
  __builtin_amdgcn_global_load_lds(
      (const __attribute__((address_space(1))) unsigned int*)g,
      (__attribute__((address_space(3))) unsigned int*)l, 16, 0, 0);
}

// Row maps for the A operand.
// RM=0 identity; RM=1 L0 (XS in (b,t) layout, seg len 1 -> R=(s*64+b)):
//   mul row = b*512 + 2s = ((R&63)<<9)|((R>>6)<<1)
// RM=2 seg-major radix-2: mul row = ((R>>6)<<7)|(R&63)
template<int RM>
__device__ __forceinline__ int rmap(int R) {
  return (RM == 0) ? R
       : (RM == 1) ? (((R & 63) << 9) | ((R >> 6) << 1))
                   : (((R >> 6) << 7) | (R & 63));
}

// ---------------------------------------------------------------------------
// K=1024 bf16 GEMM pass (m97 structure): C += A[rmap(row)] * BT^T
// 128x128 tile, 4 waves (2x2), 16x16x32 MFMA, BK=32, 2 barriers/K-step.
// Staging: global_load_lds w=16, pre-swizzled SOURCE; ds_read applies same XOR.
// ---------------------------------------------------------------------------
template<int RM>
__device__ __forceinline__ void gemm_pass(
    char* lds, f32x4 (&acc)[4][4],
    const short* __restrict__ A, const short* __restrict__ BT,
    int row0, int col0, int tid, int wave, int lane) {
  char* ldsB = lds + 8192;
  const int wm = wave >> 1, wn = wave & 1;
  const int l16 = lane & 15, kg = lane >> 4;

  for (int kt = 0; kt < 32; ++kt) {
    #pragma unroll
    for (int i = 0; i < 2; ++i) {
      int G = i * 256 + tid;
      int r = G >> 2, g = G & 3;
      int gs = g ^ ((r >> 1) & 3);
      gload16(lds + (size_t)G * 16,
              A + (size_t)rmap<RM>(row0 + r) * 1024 + kt * 32 + gs * 8);
    }
    #pragma unroll
    for (int i = 0; i < 2; ++i) {
      int G = i * 256 + tid;
      int r = G >> 2, g = G & 3;
      int gs = g ^ ((r >> 1) & 3);
      gload16(ldsB + (size_t)G * 16,
              BT + (size_t)(col0 + r) * 1024 + kt * 32 + gs * 8);
    }
    __syncthreads();   // compiler drains vmcnt before s_barrier

    bf16x8 af[4], bfr[4];
    #pragma unroll
    for (int m = 0; m < 4; ++m) {
      int row = wm * 64 + m * 16 + l16;
      int g = kg ^ ((row >> 1) & 3);
      af[m] = *(const bf16x8*)(lds + (row * 4 + g) * 16);
    }
    #pragma unroll
    for (int n = 0; n < 4; ++n) {
      int c = wn * 64 + n * 16 + l16;
      int g = kg ^ ((c >> 1) & 3);
      bfr[n] = *(const bf16x8*)(ldsB + (c * 4 + g) * 16);
    }
    #pragma unroll
    for (int m = 0; m < 4; ++m)
      #pragma unroll
      for (int n = 0; n < 4; ++n)
        acc[m][n] = __builtin_amdgcn_mfma_f32_16x16x32_bf16(af[m], bfr[n], acc[m][n], 0, 0, 0);
    __syncthreads();
  }
}

// epilogue: C/D layout col=lane&15, row=(lane>>4)*4+reg  [HW-verified]
// ADD: 0 none; 1 L0 add (XS row map +1); 2 seg add (row+64)   (adds are bf16)
// OUT: 0 bf16 C; 2 fp32 out, rows<64 only
template<int ADD, int OUT>
__device__ __forceinline__ void gemm_epi(
    f32x4 (&acc)[4][4], void* __restrict__ Cp, const short* __restrict__ AddP,
    int row0, int col0, int wave, int lane) {
  const int wm = wave >> 1, wn = wave & 1;
  const int l16 = lane & 15;
  #pragma unroll
  for (int m = 0; m < 4; ++m) {
    #pragma unroll
    for (int n = 0; n < 4; ++n) {
      const int grow0 = row0 + wm * 64 + m * 16 + ((lane >> 4) << 2);
      const int gcol  = col0 + wn * 64 + n * 16 + l16;
      #pragma unroll
      for (int r = 0; r < 4; ++r) {
        const int R = grow0 + r;
        float val = acc[m][n][r];
        if (ADD == 1) {
          int ar = (((R & 63) << 9) | ((R >> 6) << 1)) + 1;
          val += bf2fs(AddP[(size_t)ar * 1024 + gcol]);
        } else if (ADD == 2) {
          int ar = (((R >> 6) << 7) | (R & 63)) + 64;
          val += bf2fs(AddP[(size_t)ar * 1024 + gcol]);
        }
        if (OUT == 0) {
          ((short*)Cp)[(size_t)R * 1024 + gcol] = f2bfs(val);
        } else {
          if (R < 64) ((float*)Cp)[(size_t)R * 1024 + gcol] = val;
        }
      }
    }
  }
}

// ---------------- prep: WT, UT (transposed bf16), Ub, XB (bf16 casts) -------
__global__ __launch_bounds__(256) void k_prep(
    const float* __restrict__ W, const float* __restrict__ Uf,
    const float* __restrict__ X,
    short* __restrict__ WT, short* __restrict__ UT,
    short* __restrict__ Ub, short* __restrict__ XB) {
  __shared__ float tf[32][36];
  int b = blockIdx.x, t = threadIdx.x;
  if (b < 2048) {
    const float* src = (b < 1024) ? W : Uf;
    short* dst = (b < 1024) ? WT : UT;
    int bb = b & 1023;
    int i0 = (bb >> 5) * 32, j0 = (bb & 31) * 32;
    int r = t >> 3, c = (t & 7) * 4;
    *(f32x4*)&tf[r][c] = *(const f32x4*)(src + (size_t)(i0 + r) * 1024 + j0 + c);
    __syncthreads();
    s16x4 o;
    o.x = f2bfs(tf[c + 0][r]); o.y = f2bfs(tf[c + 1][r]);
    o.z = f2bfs(tf[c + 2][r]); o.w = f2bfs(tf[c + 3][r]);
    *(s16x4*)(dst + (size_t)(j0 + r) * 1024 + i0 + c) = o;
  } else if (b < 2560) {
    int q = b - 2048;
    size_t base = (size_t)q * 2048 + (size_t)t * 8;
    f32x4 a = *(const f32x4*)(Uf + base);
    f32x4 c2 = *(const f32x4*)(Uf + base + 4);
    bf16x8 o;
    o[0] = f2bfs(a.x);  o[1] = f2bfs(a.y);  o[2] = f2bfs(a.z);  o[3] = f2bfs(a.w);
    o[4] = f2bfs(c2.x); o[5] = f2bfs(c2.y); o[6] = f2bfs(c2.z); o[7] = f2bfs(c2.w);
    *(bf16x8*)(Ub + base) = o;
  } else {
    int q = b - 2560;
    size_t base = ((size_t)q * 256 + t) * 32;
    #pragma unroll
    for (int i = 0; i < 4; ++i) {
      f32x4 a = *(const f32x4*)(X + base + i * 8);
      f32x4 c2 = *(const f32x4*)(X + base + i * 8 + 4);
      bf16x8 o;
      o[0] = f2bfs(a.x);  o[1] = f2bfs(a.y);  o[2] = f2bfs(a.z);  o[3] = f2bfs(a.w);
      o[4] = f2bfs(c2.x); o[5] = f2bfs(c2.y); o[6] = f2bfs(c2.z); o[7] = f2bfs(c2.w);
      *(bf16x8*)(XB + base + i * 8) = o;
    }
  }
}

// ---------------- generic level kernel: squares (blocks<nSq) + combine ------
// Square jobs dispatched FIRST so the serial power chain starts immediately.
// nSq==128: blocks 0..63 -> P-form (gemm(sqA,sqAT)), 64..127 -> T-form.
// nSq==64 : T-form only.
template<int RM, int ADD, int OUT>
__global__ __launch_bounds__(256) void k_mm(
    const short* __restrict__ Fin, const short* __restrict__ PT,
    void* __restrict__ Fout,
    const short* __restrict__ sqA, const short* __restrict__ sqAT,
    short* __restrict__ sqP, short* __restrict__ sqPT, int nSq) {
  __shared__ __align__(16) char lds[16384];
  f32x4 acc[4][4] = {};
  int tid = threadIdx.x, wave = tid >> 6, lane = tid & 63;
  int b = blockIdx.x;
  if (b < nSq) {
    int z = (nSq == 128) ? (b >> 6) : 1;
    int q = b & 63;
    int row0 = (q >> 3) * 128, col0 = (q & 7) * 128;
    if (z == 0) {
      gemm_pass<0>(lds, acc, sqA, sqAT, row0, col0, tid, wave, lane);
      gemm_epi<0, 0>(acc, sqP, nullptr, row0, col0, wave, lane);
    } else {
      gemm_pass<0>(lds, acc, sqAT, sqA, row0, col0, tid, wave, lane);
      gemm_epi<0, 0>(acc, sqPT, nullptr, row0, col0, wave, lane);
    }
  } else {
    int c = b - nSq;
    int row0 = (c >> 3) * 128, col0 = (c & 7) * 128;   // col-fastest for L2 reuse
    gemm_pass<RM>(lds, acc, Fin, PT, row0, col0, tid, wave, lane);
    gemm_epi<ADD, OUT>(acc, Fout, Fin, row0, col0, wave, lane);
  }
}

extern "C" void kernel_launch(void* const* d_in, const int* in_sizes, int n_in,
                              void* d_out, int out_size, void* d_ws, size_t ws_size,
                              hipStream_t stream) {
  const float* X = (const float*)d_in[0];   // [64,512,1024] fp32
  const float* W = (const float*)d_in[1];   // [1024,1024] fp32
  const float* U = (const float*)d_in[2];   // [1024,1024] fp32
  float* out = (float*)d_out;               // [64,1024] fp32

  char* ws = (char*)d_ws;
  // [0,64MB): region A  = XS, then F2,F4,F6,F8
  // [64,128MB): region B = XB, then F1,F3,F5,F7
  // [128,140MB): bf16 power slots (2MB each): p0,pt0,pA,ptA,pB(=WT),ptB
  short* RA = (short*)ws;
  short* RB = (short*)(ws + ((size_t)64 << 20));
  char* pb  = ws + ((size_t)128 << 20);
  const size_t SL = (size_t)2 << 20;
  short* p0  = (short*)(pb + 0 * SL);   // U (bf16)
  short* pt0 = (short*)(pb + 1 * SL);   // U^T, later U^8T, U^64T
  short* pA  = (short*)(pb + 2 * SL);   // U^2, U^8, U^32, U^128
  short* ptA = (short*)(pb + 3 * SL);   // U^2T, U^16T, U^128T
  short* pB  = (short*)(pb + 4 * SL);   // WT first, then U^4, U^16, U^64
  short* ptB = (short*)(pb + 5 * SL);   // U^4T, U^32T, U^256T
  short* WT  = pB;                       // WT dead after k_xw launch; pB written at L0

  short* XS = RA;
  short* XB = RB;

  // L1: casts + transposes (XB cast dominates, ~190MB traffic)
  k_prep<<<6656, 256, 0, stream>>>(W, U, X, WT, pt0, p0, XB);

  // L2: XS = XB @ WT^T  (2048 blocks) + square U^2 (pA), U^2T (ptA)
  k_mm<0, 0, 0><<<2176, 256, 0, stream>>>(XB, WT, XS, p0, pt0, pA, ptA, 128);

  // L0 combine: F1 = XS[even]*U + XS[odd]  (M=16384) + square U^4 (pB,ptB)
  k_mm<1, 1, 0><<<1152, 256, 0, stream>>>(XS, pt0, RB, pA, ptA, pB, ptB, 128);

  // L1: uses U^2T (ptA); builds U^8 -> (pA, pt0)        M=8192
  k_mm<2, 2, 0><<<640, 256, 0, stream>>>(RB, ptA, RA, pB, ptB, pA, pt0, 128);
  // L2: uses U^4T (ptB); builds U^16 -> (pB, ptA)       M=4096
  k_mm<2, 2, 0><<<384, 256, 0, stream>>>(RA, ptB, RB, pA, pt0, pB, ptA, 128);
  // L3: uses U^8T (pt0); builds U^32 -> (pA, ptB)       M=2048
  k_mm<2, 2, 0><<<256, 256, 0, stream>>>(RB, pt0, RA, pB, ptA, pA, ptB, 128);
  // L4: uses U^16T (ptA); builds U^64 -> (pB, pt0)      M=1024
  k_mm<2, 2, 0><<<192, 256, 0, stream>>>(RA, ptA, RB, pA, ptB, pB, pt0, 128);
  // L5: uses U^32T (ptB); builds U^128 -> (pA, ptA)     M=512
  k_mm<2, 2, 0><<<160, 256, 0, stream>>>(RB, ptB, RA, pB, pt0, pA, ptA, 128);
  // L6: uses U^64T (pt0); builds U^256T only -> ptB     M=256
  k_mm<2, 2, 0><<<80, 256, 0, stream>>>(RA, pt0, RB, pA, ptA, nullptr, ptB, 64);
  // L7: uses U^128T (ptA)                               M=128
  k_mm<2, 2, 0><<<8, 256, 0, stream>>>(RB, ptA, RA, nullptr, nullptr, nullptr, nullptr, 0);
  // L8: uses U^256T (ptB), writes fp32 d_out rows<64    M=64
  k_mm<2, 2, 2><<<8, 256, 0, stream>>>(RA, ptB, out, nullptr, nullptr, nullptr, nullptr, 0);
}